// Round 23
// baseline (118.244 us; speedup 1.0000x reference)
//
#include <hip/hip_runtime.h>

typedef unsigned short u16;
typedef __attribute__((ext_vector_type(4))) float f32x4;
typedef __attribute__((ext_vector_type(8))) _Float16 f16x8;
typedef __attribute__((ext_vector_type(4))) unsigned short u16x4;

#define GLOAD16(g, l) __builtin_amdgcn_global_load_lds(                      \
    (const __attribute__((address_space(1))) void*)(g),                      \
    (__attribute__((address_space(3))) void*)(l), 16, 0, 0)

static __device__ __forceinline__ u16 f2h(float f) {
  _Float16 h = (_Float16)f;
  return __builtin_bit_cast(u16, h);
}

// ------------------------------------------------ prep: cvt + wtrans fused
// blocks [0,12288): convert q/k/v f32->f16 (zz = id/4096), HBM-bound ~12us.
// blocks [12288,13312): transpose+convert the 4 weight matrices.
// (R22 post-mortem: fused f32-A qkv pays ~18us inside the GEMM to save a
// 12us prep - split is net better; R12's f16 qkv hit the 2-phase ceiling.)
__global__ __launch_bounds__(256)
void prep_kernel(const float4* __restrict__ q, const float4* __restrict__ k,
                 const float4* __restrict__ v,
                 u16x4* __restrict__ oq, u16x4* __restrict__ ok,
                 u16x4* __restrict__ ov,
                 const float* __restrict__ w0, const float* __restrict__ w1,
                 const float* __restrict__ w2, const float* __restrict__ w3,
                 u16* __restrict__ t0, u16* __restrict__ t1,
                 u16* __restrict__ t2, u16* __restrict__ t3) {
  __shared__ float t[64][65];
  const int id = blockIdx.x;
  if (id < 12288) {
    const int zz = id >> 12;
    const int xx = id & 4095;
    const float4* in = zz == 0 ? q : zz == 1 ? k : v;
    u16x4* out = zz == 0 ? oq : zz == 1 ? ok : ov;
    const int i = xx * 256 + threadIdx.x;
    float4 f = in[i];
    u16x4 o;
    o[0] = f2h(f.x); o[1] = f2h(f.y); o[2] = f2h(f.z); o[3] = f2h(f.w);
    out[i] = o;
  } else {
    const int wt = id - 12288;
    const int z = wt >> 8;
    const int r2 = wt & 255;
    const float* W = z == 0 ? w0 : z == 1 ? w1 : z == 2 ? w2 : w3;
    u16* O = z == 0 ? t0 : z == 1 ? t1 : z == 2 ? t2 : t3;
    const int c = threadIdx.x & 63, r0 = threadIdx.x >> 6;
    const int by = (r2 >> 4) << 6, bx = (r2 & 15) << 6;
#pragma unroll
    for (int i = 0; i < 64; i += 4)
      t[i + r0][c] = W[(size_t)(by + i + r0) * 1024 + bx + c];
    __syncthreads();
#pragma unroll
    for (int i = 0; i < 64; i += 4)
      O[(size_t)(bx + i + r0) * 1024 + by + c] = f2h(t[c][i + r0]);
  }
}

// ---------------------------------------------------------- QKV projection
// C[4096,1024] = A_f16[4096,1024] x Bt_f16[1024,1024]^T, f16 out.
// The R22 gemm_out template applied to qkv: 128x128 tile, BK=32, f16
// inputs (R12's 39us=662TF hit the 2-phase ceiling; fused-f32 could not),
// all-GLOAD16 staging, slot-XOR swizzle on both tiles (R21: conflicts->0;
// layout (row,col16) at slot col16^((row>>1)&3), linear DMA dest +
// inverse-swizzled source + XOR'd read), single-barrier double-buffer
// (R22: barrier drain covers only loads that had a full compute phase to
// land). LDS 32KB. T1 XCD-chunk.
// z=0: Qh (pre-scaled 0.125), z=1: Kh, z=2: V transposed [b,h,hd,L].
__global__ __launch_bounds__(256)
void gemm_qkv_kernel(const u16* __restrict__ qb, const u16* __restrict__ kb,
                     const u16* __restrict__ vb,
                     const u16* __restrict__ wqt, const u16* __restrict__ wkt,
                     const u16* __restrict__ wvt,
                     u16* __restrict__ Qh, u16* __restrict__ Kh,
                     u16* __restrict__ Vt) {
  constexpr int K = 1024, N = 1024;
  __shared__ __align__(16) u16 Al[2][128 * 32];  // 2x8KB slot-XOR f16
  __shared__ __align__(16) u16 Bl[2][128 * 32];  // 2x8KB slot-XOR f16
  const int id = blockIdx.x;
  const int gtile = (id & 7) * 96 + (id >> 3);   // 768 = 8 XCD x 96
  const int z = gtile >> 8;                      // 256 tiles per z
  const int r = gtile & 255;
  const int bm = r >> 3, bn = r & 7;
  const u16* A = z == 0 ? qb : (z == 1 ? kb : vb);
  const u16* Bt = z == 0 ? wqt : (z == 1 ? wkt : wvt);
  const int tid = threadIdx.x, wave = tid >> 6, lane = tid & 63;
  const int g = lane >> 4, li = lane & 15;
  const int wr = (wave >> 1) * 64, wc = (wave & 1) * 64;
  f32x4 acc[4][4] = {};
  const char* Ab = (const char*)A;
  const char* Bb = (const char*)Bt;
  int aoff[2], boff[2];
#pragma unroll
  for (int i = 0; i < 2; ++i) {
    int p = (i * 256 + tid) * 16;
    int row = p >> 6, slot = (p >> 4) & 3;
    const int sc = (slot ^ ((row >> 1) & 3)) << 4;
    aoff[i] = (bm * 128 + row) * (K * 2) + sc;
    boff[i] = (bn * 128 + row) * (K * 2) + sc;
  }
  // prologue: tile 0 into buf0
  GLOAD16(Ab + aoff[0], (char*)Al[0] + tid * 16);
  GLOAD16(Ab + aoff[1], (char*)Al[0] + 4096 + tid * 16);
  GLOAD16(Bb + boff[0], (char*)Bl[0] + tid * 16);
  GLOAD16(Bb + boff[1], (char*)Bl[0] + 4096 + tid * 16);
  for (int k0 = 0; k0 < K; k0 += 32) {
    const int cur = (k0 >> 5) & 1;
    __syncthreads();   // buf[cur] ready (prefetch had previous compute to land)
    if (k0 + 32 < K) {
      GLOAD16(Ab + aoff[0] + (k0 + 32) * 2, (char*)Al[cur ^ 1] + tid * 16);
      GLOAD16(Ab + aoff[1] + (k0 + 32) * 2, (char*)Al[cur ^ 1] + 4096 + tid * 16);
      GLOAD16(Bb + boff[0] + (k0 + 32) * 2, (char*)Bl[cur ^ 1] + tid * 16);
      GLOAD16(Bb + boff[1] + (k0 + 32) * 2, (char*)Bl[cur ^ 1] + 4096 + tid * 16);
    }
    f16x8 af[4], bf[4];
#pragma unroll
    for (int m = 0; m < 4; ++m) {
      const int row = wr + m * 16 + li;
      af[m] = *(const f16x8*)((const char*)Al[cur] + (row << 6) +
                              ((g ^ ((row >> 1) & 3)) << 4));
    }
#pragma unroll
    for (int n = 0; n < 4; ++n) {
      const int row = wc + n * 16 + li;
      bf[n] = *(const f16x8*)((const char*)Bl[cur] + (row << 6) +
                              ((g ^ ((row >> 1) & 3)) << 4));
    }
#pragma unroll
    for (int m = 0; m < 4; ++m)
#pragma unroll
      for (int n = 0; n < 4; ++n)
        acc[m][n] = __builtin_amdgcn_mfma_f32_16x16x32_f16(af[m], bf[n], acc[m][n], 0, 0, 0);
  }
  if (z <= 1) {
    u16* C = z == 0 ? Qh : Kh;
    const float cs = z == 0 ? 0.125f : 1.0f;   // fold attn scale into Q
#pragma unroll
    for (int m = 0; m < 4; ++m) {
      const int row = bm * 128 + wr + m * 16 + g * 4;
#pragma unroll
      for (int n = 0; n < 4; ++n) {
        const int col = bn * 128 + wc + n * 16 + li;
#pragma unroll
        for (int j = 0; j < 4; ++j)
          C[(size_t)(row + j) * N + col] = f2h(acc[m][n][j] * cs);
      }
    }
  } else {
#pragma unroll
    for (int m = 0; m < 4; ++m) {
      const int row = bm * 128 + wr + m * 16 + g * 4;  // = b*1024 + l, l%4==0
      const int bb = row >> 10, l = row & 1023;
#pragma unroll
      for (int n = 0; n < 4; ++n) {
        const int col = bn * 128 + wc + n * 16 + li;   // h*64 + hd
        u16x4 pk;
#pragma unroll
        for (int j = 0; j < 4; ++j) pk[j] = f2h(acc[m][n][j]);
        *(u16x4*)(Vt + (size_t)((bb * 16 + (col >> 6)) * 64 + (col & 63)) * 1024 + l) = pk;
      }
    }
  }
}

// ----------------------------------------------------- V column means
__global__ __launch_bounds__(256)
void vmean_kernel(const u16* __restrict__ Vt, float* __restrict__ Vm) {
  const int hh = blockIdx.x;
  const int t = threadIdx.x;
  const int hd = t >> 2, part = t & 3;
  const u16* row = Vt + ((size_t)(hh * 64 + hd) << 10) + part * 256;
  float acc = 0.f;
#pragma unroll
  for (int i = 0; i < 256; i += 8) {
    f16x8 v = *(const f16x8*)(row + i);
#pragma unroll
    for (int e = 0; e < 8; ++e) acc += (float)v[e];
  }
  acc += __shfl_xor(acc, 1);
  acc += __shfl_xor(acc, 2);
  if (part == 0) Vm[hh * 64 + hd] = acc * (1.f / 1024.f);
}

// ------------------------------------------------------------- attention
// grid 4096, 1-wave blocks, no barriers, K/V direct from global/L2
// (hh = id&63 keeps a head on one XCD). __launch_bounds__(64), no min-waves
// (R8's cap collapsed the prefetch pipeline). Per tile: QK MFMA -> issue
// K(t+1)+V(t) -> defer-max softmax -> P via swizzled LDS -> PV MFMA
// (+ones-MFMA denominator). Mask semantics (f32 -1e9 absorption,
// R5-verified): rows >= vl = uniform V mean (Vmean); cols masked last tile.
__global__ __launch_bounds__(64)
void attn_kernel(const u16* __restrict__ Qh, const u16* __restrict__ Kh,
                 const u16* __restrict__ Vt, const float* __restrict__ Vm,
                 const int* __restrict__ vlens, u16* __restrict__ AO) {
  constexpr int L = 1024, D = 1024, HD = 64;
  __shared__ __align__(16) u16 Pl[16 * 64];   // 2KB, wave-private
  const int id = blockIdx.x;
  const int hh = id & 63;           // b*16 + h
  const int rq = id >> 6;           // 0..63
  const int b = hh >> 4;
  const int lane = threadIdx.x;
  const int g = lane >> 4, li = lane & 15;
  const int qrow0 = rq * 16;
  const int hcol = (hh & 15) * HD;
  const int vl = vlens[b];

  if (qrow0 >= vl) {
#pragma unroll
    for (int n = 0; n < 4; ++n) {
      const u16 o = f2h(Vm[hh * 64 + n * 16 + li]);
#pragma unroll
      for (int j = 0; j < 4; ++j) {
        const int qr = qrow0 + g * 4 + j;
        AO[(size_t)(b * L + qr) * D + hcol + n * 16 + li] = o;
      }
    }
    return;
  }

  const bool mixed = (qrow0 + 15) >= vl;
  const int nt = (vl + 63) >> 6;

  f16x8 aq[2];
#pragma unroll
  for (int ks = 0; ks < 2; ++ks)
    aq[ks] = *(const f16x8*)(Qh + (size_t)(b * L + qrow0 + li) * D +
                             hcol + ks * 32 + g * 8);
  f16x8 ones;
#pragma unroll
  for (int e = 0; e < 8; ++e) ones[e] = (_Float16)1.0f;

  f32x4 accO[4] = {};
  f32x4 accL = {};
  float mrun[4];
#pragma unroll
  for (int j = 0; j < 4; ++j) mrun[j] = -3e38f;

  char* Pw = (char*)Pl;  // [16][128B], swizzled
  const u16* Kbase = Kh + ((size_t)(b * L) << 10) + hcol;  // rows stride D
  const u16* Vbase = Vt + ((size_t)(hh * HD) << 10);       // rows stride L

  // prologue: K fragments for tile 0
  f16x8 kf[2][4];
#pragma unroll
  for (int ks = 0; ks < 2; ++ks)
#pragma unroll
    for (int n = 0; n < 4; ++n)
      kf[ks][n] = *(const f16x8*)(Kbase + (size_t)(n * 16 + li) * D +
                                  ks * 32 + g * 8);

  for (int kt = 0; kt < nt; ++kt) {
    // S = Q K^T (Q pre-scaled by 0.125)
    f32x4 s[4] = {};
#pragma unroll
    for (int ks = 0; ks < 2; ++ks)
#pragma unroll
      for (int n = 0; n < 4; ++n)
        s[n] = __builtin_amdgcn_mfma_f32_16x16x32_f16(aq[ks], kf[ks][n], s[n], 0, 0, 0);
    // issue next tile's K loads (consumed next iteration)
    if (kt + 1 < nt) {
      const int kb2 = (kt + 1) * 64;
#pragma unroll
      for (int ks = 0; ks < 2; ++ks)
#pragma unroll
        for (int n = 0; n < 4; ++n)
          kf[ks][n] = *(const f16x8*)(Kbase + (size_t)(kb2 + n * 16 + li) * D +
                                      ks * 32 + g * 8);
    }
    // issue this tile's V loads (latency hides under softmax + P write)
    const int kbase = kt * 64;
    f16x8 vf[2][4];
#pragma unroll
    for (int ks = 0; ks < 2; ++ks)
#pragma unroll
      for (int n = 0; n < 4; ++n)
        vf[ks][n] = *(const f16x8*)(Vbase + (size_t)(n * 16 + li) * L +
                                    kbase + ks * 32 + g * 8);
    // column mask only in the final (partial) tile
    if (kt == nt - 1) {
#pragma unroll
      for (int n = 0; n < 4; ++n)
        if (kbase + n * 16 + li >= vl) {
#pragma unroll
          for (int j = 0; j < 4; ++j) s[n][j] = -1e30f;
        }
    }
    // defer-max online softmax
    float mx[4];
#pragma unroll
    for (int j = 0; j < 4; ++j)
      mx[j] = fmaxf(fmaxf(s[0][j], s[1][j]), fmaxf(s[2][j], s[3][j]));
    const bool ok = mx[0] <= mrun[0] + 8.f && mx[1] <= mrun[1] + 8.f &&
                    mx[2] <= mrun[2] + 8.f && mx[3] <= mrun[3] + 8.f;
    if (!__all(ok)) {
#pragma unroll
      for (int j = 0; j < 4; ++j) {
        float r = mx[j];
#pragma unroll
        for (int d = 1; d < 16; d <<= 1) r = fmaxf(r, __shfl_xor(r, d));
        const float mnew = fmaxf(mrun[j], r);
        const float fac = __expf(mrun[j] - mnew);
        mrun[j] = mnew;
        accL[j] *= fac;
#pragma unroll
        for (int n = 0; n < 4; ++n) accO[n][j] *= fac;
      }
    }
    // exp (bounded by e^8) + P write (wave-private swizzled LDS)
#pragma unroll
    for (int n = 0; n < 4; ++n) {
#pragma unroll
      for (int j = 0; j < 4; ++j) {
        const float p = __expf(s[n][j] - mrun[j]);
        const int row = g * 4 + j;
        int off = (row << 7) + (n * 16 + li) * 2;
        off ^= (row & 7) << 4;
        *(u16*)(Pw + off) = f2h(p);
      }
    }
    // O += P V ; denominator via ones-MFMA (every lane gets the row-sum)
#pragma unroll
    for (int ks2 = 0; ks2 < 2; ++ks2) {
      f16x8 pa;
      {
        int off = (li << 7) + ks2 * 64 + g * 16;
        off ^= (li & 7) << 4;
        pa = *(const f16x8*)(Pw + off);
      }
#pragma unroll
      for (int n = 0; n < 4; ++n)
        accO[n] = __builtin_amdgcn_mfma_f32_16x16x32_f16(pa, vf[ks2][n], accO[n], 0, 0, 0);
      accL = __builtin_amdgcn_mfma_f32_16x16x32_f16(pa, ones, accL, 0, 0, 0);
    }
  }
  // epilogue: divide by row-sum; uniform rows get Vmean
  float vmv[4];
  if (mixed) {
#pragma unroll
    for (int n = 0; n < 4; ++n) vmv[n] = Vm[hh * 64 + n * 16 + li];
  }
#pragma unroll
  for (int j = 0; j < 4; ++j) {
    const float inv = 1.f / accL[j];
    const int qr = qrow0 + g * 4 + j;
#pragma unroll
    for (int n = 0; n < 4; ++n) {
      float o = accO[n][j] * inv;
      if (mixed && qr >= vl) o = vmv[n];
      AO[(size_t)(b * L + qr) * D + hcol + n * 16 + li] = f2h(o);
    }
  }
}

// ------------------------------------------------------- output projection
// R22-identical: single-barrier dbuf + slot-XOR (passing, contributed the
// R22 total win). 32KB LDS, grid 256.
__global__ __launch_bounds__(256)
void gemm_out_kernel(const u16* __restrict__ A, const u16* __restrict__ Bt,
                     float* __restrict__ C) {
  constexpr int K = 1024, N = 1024;
  __shared__ __align__(16) u16 Al[2][128 * 32];
  __shared__ __align__(16) u16 Bl[2][128 * 32];
  const int id = blockIdx.x;
  const int gtile = (id & 7) * 32 + (id >> 3);   // 256 = 8 XCD x 32
  const int bm = gtile >> 3, bn = gtile & 7;
  const int tid = threadIdx.x, wave = tid >> 6, lane = tid & 63;
  const int g = lane >> 4, li = lane & 15;
  const int wr = (wave >> 1) * 64, wc = (wave & 1) * 64;
  f32x4 acc[4][4] = {};
  const char* Ab = (const char*)A;
  const char* Bb = (const char*)Bt;
  int aoff[2], boff[2];
#pragma unroll
  for (int i = 0; i < 2; ++i) {
    int p = (i * 256 + tid) * 16;
    int row = p >> 6, slot = (p >> 4) & 3;
    const int sc = (slot ^ ((row >> 1) & 3)) << 4;
    aoff[i] = (bm * 128 + row) * (K * 2) + sc;
    boff[i] = (bn * 128 + row) * (K * 2) + sc;
  }
  GLOAD16(Ab + aoff[0], (char*)Al[0] + tid * 16);
  GLOAD16(Ab + aoff[1], (char*)Al[0] + 4096 + tid * 16);
  GLOAD16(Bb + boff[0], (char*)Bl[0] + tid * 16);
  GLOAD16(Bb + boff[1], (char*)Bl[0] + 4096 + tid * 16);
  for (int k0 = 0; k0 < K; k0 += 32) {
    const int cur = (k0 >> 5) & 1;
    __syncthreads();
    if (k0 + 32 < K) {
      GLOAD16(Ab + aoff[0] + (k0 + 32) * 2, (char*)Al[cur ^ 1] + tid * 16);
      GLOAD16(Ab + aoff[1] + (k0 + 32) * 2, (char*)Al[cur ^ 1] + 4096 + tid * 16);
      GLOAD16(Bb + boff[0] + (k0 + 32) * 2, (char*)Bl[cur ^ 1] + tid * 16);
      GLOAD16(Bb + boff[1] + (k0 + 32) * 2, (char*)Bl[cur ^ 1] + 4096 + tid * 16);
    }
    f16x8 af[4], bf[4];
#pragma unroll
    for (int m = 0; m < 4; ++m) {
      const int row = wr + m * 16 + li;
      af[m] = *(const f16x8*)((const char*)Al[cur] + (row << 6) +
                              ((g ^ ((row >> 1) & 3)) << 4));
    }
#pragma unroll
    for (int n = 0; n < 4; ++n) {
      const int row = wc + n * 16 + li;
      bf[n] = *(const f16x8*)((const char*)Bl[cur] + (row << 6) +
                              ((g ^ ((row >> 1) & 3)) << 4));
    }
#pragma unroll
    for (int m = 0; m < 4; ++m)
#pragma unroll
      for (int n = 0; n < 4; ++n)
        acc[m][n] = __builtin_amdgcn_mfma_f32_16x16x32_f16(af[m], bf[n], acc[m][n], 0, 0, 0);
  }
#pragma unroll
  for (int m = 0; m < 4; ++m) {
    const int row = bm * 128 + wr + m * 16 + g * 4;
#pragma unroll
    for (int n = 0; n < 4; ++n) {
      const int col = bn * 128 + wc + n * 16 + li;
#pragma unroll
      for (int j = 0; j < 4; ++j)
        C[(size_t)(row + j) * N + col] = acc[m][n][j];
    }
  }
}

// ---------------------------------------------------------------- launch
extern "C" void kernel_launch(void* const* d_in, const int* in_sizes, int n_in,
                              void* d_out, int out_size, void* d_ws, size_t ws_size,
                              hipStream_t stream) {
  (void)in_sizes; (void)n_in; (void)out_size; (void)ws_size;
  const float* q = (const float*)d_in[0];
  const float* k = (const float*)d_in[1];
  const float* v = (const float*)d_in[2];
  const float* wq = (const float*)d_in[3];
  const float* wk = (const float*)d_in[4];
  const float* wv = (const float*)d_in[5];
  const float* wo = (const float*)d_in[6];
  const int* vl = (const int*)d_in[8];

  char* ws = (char*)d_ws;
  const size_t MB = 1u << 20;
  u16* qb = (u16*)(ws + 0 * MB);    // 8 MB each (f16 activations)
  u16* kb = (u16*)(ws + 8 * MB);
  u16* vb = (u16*)(ws + 16 * MB);
  u16* wqt = (u16*)(ws + 24 * MB);  // 2 MB each, transposed fp16
  u16* wkt = (u16*)(ws + 26 * MB);
  u16* wvt = (u16*)(ws + 28 * MB);
  u16* wot = (u16*)(ws + 30 * MB);
  u16* Qh = (u16*)(ws + 32 * MB);
  u16* Kh = (u16*)(ws + 40 * MB);
  u16* Vt = (u16*)(ws + 48 * MB);
  float* Vm = (float*)(ws + 56 * MB);  // 16 KB
  u16* AO = qb;  // reuse (qb dead after projections)

  prep_kernel<<<13312, 256, 0, stream>>>(
      (const float4*)q, (const float4*)k, (const float4*)v,
      (u16x4*)qb, (u16x4*)kb, (u16x4*)vb,
      wq, wk, wv, wo, wqt, wkt, wvt, wot);
  gemm_qkv_kernel<<<768, 256, 0, stream>>>(qb, kb, vb, wqt, wkt, wvt, Qh, Kh, Vt);
  vmean_kernel<<<64, 256, 0, stream>>>(Vt, Vm);
  attn_kernel<<<4096, 64, 0, stream>>>(Qh, Kh, Vt, Vm, vl, AO);
  gemm_out_kernel<<<256, 256, 0, stream>>>(AO, wot, (float*)d_out);
}

// Round 24
// 107.312 us; speedup vs baseline: 1.1019x; 1.1019x over previous
//
#include <hip/hip_runtime.h>

typedef unsigned short u16;
typedef __attribute__((ext_vector_type(4))) float f32x4;
typedef __attribute__((ext_vector_type(8))) _Float16 f16x8;
typedef __attribute__((ext_vector_type(4))) unsigned short u16x4;

#define GLOAD16(g, l) __builtin_amdgcn_global_load_lds(                      \
    (const __attribute__((address_space(1))) void*)(g),                      \
    (__attribute__((address_space(3))) void*)(l), 16, 0, 0)

static __device__ __forceinline__ u16 f2h(float f) {
  _Float16 h = (_Float16)f;
  return __builtin_bit_cast(u16, h);
}

// ------------------------------------------------- weight transpose+convert
__global__ __launch_bounds__(256)
void wtrans_kernel(const float* __restrict__ w0, const float* __restrict__ w1,
                   const float* __restrict__ w2, const float* __restrict__ w3,
                   u16* __restrict__ o0, u16* __restrict__ o1,
                   u16* __restrict__ o2, u16* __restrict__ o3) {
  const int z = blockIdx.z;
  const float* W = z == 0 ? w0 : z == 1 ? w1 : z == 2 ? w2 : w3;
  u16* O = z == 0 ? o0 : z == 1 ? o1 : z == 2 ? o2 : o3;
  __shared__ float t[64][65];
  const int c = threadIdx.x & 63, r0 = threadIdx.x >> 6;
  const int by = blockIdx.y * 64, bx = blockIdx.x * 64;
#pragma unroll
  for (int i = 0; i < 64; i += 4)
    t[i + r0][c] = W[(size_t)(by + i + r0) * 1024 + bx + c];
  __syncthreads();
#pragma unroll
  for (int i = 0; i < 64; i += 4)
    O[(size_t)(bx + i + r0) * 1024 + by + c] = f2h(t[c][i + r0]);
}

// ---------------------------------------------------------- QKV projection
// R22-exact fused-f32-A reg-staged qkv (best total 107.9us) + BALANCED
// vl-tile-skip. Diagonal T1 map: xcd = id&7; per z each XCD owns 4 bm's,
// one per batch, at row-offset ro=(xcd+b)&7 -> skip load (Q: ro*128>=vl,
// K: ro*128>=ceil64(vl), V: never) is even across XCDs (R12's z-major
// chunks emptied whole XCDs -> neutral). Correctness = R12-proven: dead
// Qh rows feed only accumulators overwritten by the Vmean path; all K
// rows < ceil64(vl) are written. ~28% of qkv tiles skipped (E[vl]~512).
// z=0: Qh (pre-scaled 0.125), z=1: Kh, z=2: V transposed [b,h,hd,L].
__global__ __launch_bounds__(256)
void gemm_qkv_kernel(const float* __restrict__ qf, const float* __restrict__ kf_,
                     const float* __restrict__ vf_,
                     const u16* __restrict__ wqt, const u16* __restrict__ wkt,
                     const u16* __restrict__ wvt,
                     u16* __restrict__ Qh, u16* __restrict__ Kh,
                     u16* __restrict__ Vt, const int* __restrict__ vlens) {
  constexpr int K = 1024, N = 1024;
  __shared__ __align__(16) u16 Al[2][128 * 32];  // 2x8KB slot-XOR f16
  __shared__ __align__(16) u16 Bl[2][128 * 32];  // 2x8KB slot-XOR f16
  const int id = blockIdx.x;
  const int xcd = id & 7;
  const int j = id >> 3;            // 0..95
  const int z = j >> 5;             // 0..2 (32 tiles per z per XCD)
  const int w = j & 31;
  const int b = w >> 3;             // batch 0..3
  const int bn = w & 7;
  const int ro = (xcd + b) & 7;     // diagonal row-offset within batch
  const int bm = b * 8 + ro;
  // balanced vl skip (block-uniform, before any barrier)
  const int vl = vlens[b];
  if (z == 0 && ro * 128 >= vl) return;
  if (z == 1 && ro * 128 >= ((vl + 63) & ~63)) return;
  const float* A = z == 0 ? qf : (z == 1 ? kf_ : vf_);
  const u16* Bt = z == 0 ? wqt : (z == 1 ? wkt : wvt);
  const int tid = threadIdx.x, wave = tid >> 6, lane = tid & 63;
  const int g = lane >> 4, li = lane & 15;
  const int wr = (wave >> 1) * 64, wc = (wave & 1) * 64;
  f32x4 acc[4][4] = {};
  const char* Ab = (const char*)A;
  const char* Bb = (const char*)Bt;
  // A reg-stage (R21): dest chunks tid*16 and 4096+tid*16 (linear writes,
  // conflict-free); logical col16 cc = (tid&3) ^ ((r0>>1)&3).
  const int r0 = tid >> 2, s0 = tid & 3;
  const int cc = s0 ^ ((r0 >> 1) & 3);
  const char* Ag0 = Ab + (size_t)(bm * 128 + r0) * 4096 + cc * 32;
  const char* Ag1 = Ab + (size_t)(bm * 128 + 64 + r0) * 4096 + cc * 32;
  int boff[2];
#pragma unroll
  for (int i = 0; i < 2; ++i) {
    int p = (i * 256 + tid) * 16;
    int row = p >> 6, slot = (p >> 4) & 3;
    boff[i] = (bn * 128 + row) * (K * 2) + ((slot ^ ((row >> 1) & 3)) << 4);
  }
  // prologue: A(0) regs + B(0) DMA into buf0
  f32x4 ra[4];
  ra[0] = *(const f32x4*)(Ag0);
  ra[1] = *(const f32x4*)(Ag0 + 16);
  ra[2] = *(const f32x4*)(Ag1);
  ra[3] = *(const f32x4*)(Ag1 + 16);
  GLOAD16(Bb + boff[0], (char*)Bl[0] + tid * 16);
  GLOAD16(Bb + boff[1], (char*)Bl[0] + 4096 + tid * 16);
  for (int k0 = 0; k0 < K; k0 += 32) {
    const int cur = (k0 >> 5) & 1;
    // stage A(t) into Al[cur] (waits ra(t), which had compute(t-1) to land)
    f16x8 w0, w1;
#pragma unroll
    for (int e = 0; e < 4; ++e) {
      w0[e] = (_Float16)ra[0][e];
      w0[e + 4] = (_Float16)ra[1][e];
      w1[e] = (_Float16)ra[2][e];
      w1[e + 4] = (_Float16)ra[3][e];
    }
    *(f16x8*)((char*)Al[cur] + tid * 16) = w0;
    *(f16x8*)((char*)Al[cur] + 4096 + tid * 16) = w1;
    __syncthreads();   // single barrier: B(t) + ds_writes ready for all waves
    // prefetch next tile (lands across the compute phase below)
    if (k0 + 32 < K) {
      GLOAD16(Bb + boff[0] + (k0 + 32) * 2, (char*)Bl[cur ^ 1] + tid * 16);
      GLOAD16(Bb + boff[1] + (k0 + 32) * 2, (char*)Bl[cur ^ 1] + 4096 + tid * 16);
      ra[0] = *(const f32x4*)(Ag0 + (k0 + 32) * 4);
      ra[1] = *(const f32x4*)(Ag0 + (k0 + 32) * 4 + 16);
      ra[2] = *(const f32x4*)(Ag1 + (k0 + 32) * 4);
      ra[3] = *(const f32x4*)(Ag1 + (k0 + 32) * 4 + 16);
    }
    // compute(t)
    f16x8 af[4], bf[4];
#pragma unroll
    for (int m = 0; m < 4; ++m) {
      const int row = wr + m * 16 + li;
      af[m] = *(const f16x8*)((const char*)Al[cur] + (row << 6) +
                              ((g ^ ((row >> 1) & 3)) << 4));
    }
#pragma unroll
    for (int n = 0; n < 4; ++n) {
      const int row = wc + n * 16 + li;
      bf[n] = *(const f16x8*)((const char*)Bl[cur] + (row << 6) +
                              ((g ^ ((row >> 1) & 3)) << 4));
    }
#pragma unroll
    for (int m = 0; m < 4; ++m)
#pragma unroll
      for (int n = 0; n < 4; ++n)
        acc[m][n] = __builtin_amdgcn_mfma_f32_16x16x32_f16(af[m], bf[n], acc[m][n], 0, 0, 0);
  }
  if (z <= 1) {
    u16* C = z == 0 ? Qh : Kh;
    const float cs = z == 0 ? 0.125f : 1.0f;   // fold attn scale into Q
#pragma unroll
    for (int m = 0; m < 4; ++m) {
      const int row = bm * 128 + wr + m * 16 + g * 4;
#pragma unroll
      for (int n = 0; n < 4; ++n) {
        const int col = bn * 128 + wc + n * 16 + li;
#pragma unroll
        for (int jj = 0; jj < 4; ++jj)
          C[(size_t)(row + jj) * N + col] = f2h(acc[m][n][jj] * cs);
      }
    }
  } else {
#pragma unroll
    for (int m = 0; m < 4; ++m) {
      const int row = bm * 128 + wr + m * 16 + g * 4;  // = b*1024 + l, l%4==0
      const int bb = row >> 10, l = row & 1023;
#pragma unroll
      for (int n = 0; n < 4; ++n) {
        const int col = bn * 128 + wc + n * 16 + li;   // h*64 + hd
        u16x4 pk;
#pragma unroll
        for (int jj = 0; jj < 4; ++jj) pk[jj] = f2h(acc[m][n][jj]);
        *(u16x4*)(Vt + (size_t)((bb * 16 + (col >> 6)) * 64 + (col & 63)) * 1024 + l) = pk;
      }
    }
  }
}

// ----------------------------------------------------- V column means
__global__ __launch_bounds__(256)
void vmean_kernel(const u16* __restrict__ Vt, float* __restrict__ Vm) {
  const int hh = blockIdx.x;
  const int t = threadIdx.x;
  const int hd = t >> 2, part = t & 3;
  const u16* row = Vt + ((size_t)(hh * 64 + hd) << 10) + part * 256;
  float acc = 0.f;
#pragma unroll
  for (int i = 0; i < 256; i += 8) {
    f16x8 v = *(const f16x8*)(row + i);
#pragma unroll
    for (int e = 0; e < 8; ++e) acc += (float)v[e];
  }
  acc += __shfl_xor(acc, 1);
  acc += __shfl_xor(acc, 2);
  if (part == 0) Vm[hh * 64 + hd] = acc * (1.f / 1024.f);
}

// ------------------------------------------------------------- attention
// grid 4096, 1-wave blocks, no barriers, K/V direct from global/L2
// (hh = id&63 keeps a head on one XCD). __launch_bounds__(64), no min-waves
// (R8's cap collapsed the prefetch pipeline). Per tile: QK MFMA -> issue
// K(t+1)+V(t) -> defer-max softmax -> P via swizzled LDS -> PV MFMA
// (+ones-MFMA denominator). Mask semantics (f32 -1e9 absorption,
// R5-verified): rows >= vl = uniform V mean (Vmean); cols masked last tile.
__global__ __launch_bounds__(64)
void attn_kernel(const u16* __restrict__ Qh, const u16* __restrict__ Kh,
                 const u16* __restrict__ Vt, const float* __restrict__ Vm,
                 const int* __restrict__ vlens, u16* __restrict__ AO) {
  constexpr int L = 1024, D = 1024, HD = 64;
  __shared__ __align__(16) u16 Pl[16 * 64];   // 2KB, wave-private
  const int id = blockIdx.x;
  const int hh = id & 63;           // b*16 + h
  const int rq = id >> 6;           // 0..63
  const int b = hh >> 4;
  const int lane = threadIdx.x;
  const int g = lane >> 4, li = lane & 15;
  const int qrow0 = rq * 16;
  const int hcol = (hh & 15) * HD;
  const int vl = vlens[b];

  if (qrow0 >= vl) {
#pragma unroll
    for (int n = 0; n < 4; ++n) {
      const u16 o = f2h(Vm[hh * 64 + n * 16 + li]);
#pragma unroll
      for (int j = 0; j < 4; ++j) {
        const int qr = qrow0 + g * 4 + j;
        AO[(size_t)(b * L + qr) * D + hcol + n * 16 + li] = o;
      }
    }
    return;
  }

  const bool mixed = (qrow0 + 15) >= vl;
  const int nt = (vl + 63) >> 6;

  f16x8 aq[2];
#pragma unroll
  for (int ks = 0; ks < 2; ++ks)
    aq[ks] = *(const f16x8*)(Qh + (size_t)(b * L + qrow0 + li) * D +
                             hcol + ks * 32 + g * 8);
  f16x8 ones;
#pragma unroll
  for (int e = 0; e < 8; ++e) ones[e] = (_Float16)1.0f;

  f32x4 accO[4] = {};
  f32x4 accL = {};
  float mrun[4];
#pragma unroll
  for (int j = 0; j < 4; ++j) mrun[j] = -3e38f;

  char* Pw = (char*)Pl;  // [16][128B], swizzled
  const u16* Kbase = Kh + ((size_t)(b * L) << 10) + hcol;  // rows stride D
  const u16* Vbase = Vt + ((size_t)(hh * HD) << 10);       // rows stride L

  // prologue: K fragments for tile 0
  f16x8 kf[2][4];
#pragma unroll
  for (int ks = 0; ks < 2; ++ks)
#pragma unroll
    for (int n = 0; n < 4; ++n)
      kf[ks][n] = *(const f16x8*)(Kbase + (size_t)(n * 16 + li) * D +
                                  ks * 32 + g * 8);

  for (int kt = 0; kt < nt; ++kt) {
    // S = Q K^T (Q pre-scaled by 0.125)
    f32x4 s[4] = {};
#pragma unroll
    for (int ks = 0; ks < 2; ++ks)
#pragma unroll
      for (int n = 0; n < 4; ++n)
        s[n] = __builtin_amdgcn_mfma_f32_16x16x32_f16(aq[ks], kf[ks][n], s[n], 0, 0, 0);
    // issue next tile's K loads (consumed next iteration)
    if (kt + 1 < nt) {
      const int kb2 = (kt + 1) * 64;
#pragma unroll
      for (int ks = 0; ks < 2; ++ks)
#pragma unroll
        for (int n = 0; n < 4; ++n)
          kf[ks][n] = *(const f16x8*)(Kbase + (size_t)(kb2 + n * 16 + li) * D +
                                      ks * 32 + g * 8);
    }
    // issue this tile's V loads (latency hides under softmax + P write)
    const int kbase = kt * 64;
    f16x8 vf[2][4];
#pragma unroll
    for (int ks = 0; ks < 2; ++ks)
#pragma unroll
      for (int n = 0; n < 4; ++n)
        vf[ks][n] = *(const f16x8*)(Vbase + (size_t)(n * 16 + li) * L +
                                    kbase + ks * 32 + g * 8);
    // column mask only in the final (partial) tile
    if (kt == nt - 1) {
#pragma unroll
      for (int n = 0; n < 4; ++n)
        if (kbase + n * 16 + li >= vl) {
#pragma unroll
          for (int j = 0; j < 4; ++j) s[n][j] = -1e30f;
        }
    }
    // defer-max online softmax
    float mx[4];
#pragma unroll
    for (int j = 0; j < 4; ++j)
      mx[j] = fmaxf(fmaxf(s[0][j], s[1][j]), fmaxf(s[2][j], s[3][j]));
    const bool ok = mx[0] <= mrun[0] + 8.f && mx[1] <= mrun[1] + 8.f &&
                    mx[2] <= mrun[2] + 8.f && mx[3] <= mrun[3] + 8.f;
    if (!__all(ok)) {
#pragma unroll
      for (int j = 0; j < 4; ++j) {
        float r = mx[j];
#pragma unroll
        for (int d = 1; d < 16; d <<= 1) r = fmaxf(r, __shfl_xor(r, d));
        const float mnew = fmaxf(mrun[j], r);
        const float fac = __expf(mrun[j] - mnew);
        mrun[j] = mnew;
        accL[j] *= fac;
#pragma unroll
        for (int n = 0; n < 4; ++n) accO[n][j] *= fac;
      }
    }
    // exp (bounded by e^8) + P write (wave-private swizzled LDS)
#pragma unroll
    for (int n = 0; n < 4; ++n) {
#pragma unroll
      for (int j = 0; j < 4; ++j) {
        const float p = __expf(s[n][j] - mrun[j]);
        const int row = g * 4 + j;
        int off = (row << 7) + (n * 16 + li) * 2;
        off ^= (row & 7) << 4;
        *(u16*)(Pw + off) = f2h(p);
      }
    }
    // O += P V ; denominator via ones-MFMA (every lane gets the row-sum)
#pragma unroll
    for (int ks2 = 0; ks2 < 2; ++ks2) {
      f16x8 pa;
      {
        int off = (li << 7) + ks2 * 64 + g * 16;
        off ^= (li & 7) << 4;
        pa = *(const f16x8*)(Pw + off);
      }
#pragma unroll
      for (int n = 0; n < 4; ++n)
        accO[n] = __builtin_amdgcn_mfma_f32_16x16x32_f16(pa, vf[ks2][n], accO[n], 0, 0, 0);
      accL = __builtin_amdgcn_mfma_f32_16x16x32_f16(pa, ones, accL, 0, 0, 0);
    }
  }
  // epilogue: divide by row-sum; uniform rows get Vmean
  float vmv[4];
  if (mixed) {
#pragma unroll
    for (int n = 0; n < 4; ++n) vmv[n] = Vm[hh * 64 + n * 16 + li];
  }
#pragma unroll
  for (int j = 0; j < 4; ++j) {
    const float inv = 1.f / accL[j];
    const int qr = qrow0 + g * 4 + j;
#pragma unroll
    for (int n = 0; n < 4; ++n) {
      float o = accO[n][j] * inv;
      if (mixed && qr >= vl) o = vmv[n];
      AO[(size_t)(b * L + qr) * D + hcol + n * 16 + li] = f2h(o);
    }
  }
}

// ------------------------------------------------------- output projection
// R22-identical: single-barrier dbuf + slot-XOR. 32KB LDS, grid 256.
__global__ __launch_bounds__(256)
void gemm_out_kernel(const u16* __restrict__ A, const u16* __restrict__ Bt,
                     float* __restrict__ C) {
  constexpr int K = 1024, N = 1024;
  __shared__ __align__(16) u16 Al[2][128 * 32];
  __shared__ __align__(16) u16 Bl[2][128 * 32];
  const int id = blockIdx.x;
  const int gtile = (id & 7) * 32 + (id >> 3);   // 256 = 8 XCD x 32
  const int bm = gtile >> 3, bn = gtile & 7;
  const int tid = threadIdx.x, wave = tid >> 6, lane = tid & 63;
  const int g = lane >> 4, li = lane & 15;
  const int wr = (wave >> 1) * 64, wc = (wave & 1) * 64;
  f32x4 acc[4][4] = {};
  const char* Ab = (const char*)A;
  const char* Bb = (const char*)Bt;
  int aoff[2], boff[2];
#pragma unroll
  for (int i = 0; i < 2; ++i) {
    int p = (i * 256 + tid) * 16;
    int row = p >> 6, slot = (p >> 4) & 3;
    const int sc = (slot ^ ((row >> 1) & 3)) << 4;
    aoff[i] = (bm * 128 + row) * (K * 2) + sc;
    boff[i] = (bn * 128 + row) * (K * 2) + sc;
  }
  GLOAD16(Ab + aoff[0], (char*)Al[0] + tid * 16);
  GLOAD16(Ab + aoff[1], (char*)Al[0] + 4096 + tid * 16);
  GLOAD16(Bb + boff[0], (char*)Bl[0] + tid * 16);
  GLOAD16(Bb + boff[1], (char*)Bl[0] + 4096 + tid * 16);
  for (int k0 = 0; k0 < K; k0 += 32) {
    const int cur = (k0 >> 5) & 1;
    __syncthreads();
    if (k0 + 32 < K) {
      GLOAD16(Ab + aoff[0] + (k0 + 32) * 2, (char*)Al[cur ^ 1] + tid * 16);
      GLOAD16(Ab + aoff[1] + (k0 + 32) * 2, (char*)Al[cur ^ 1] + 4096 + tid * 16);
      GLOAD16(Bb + boff[0] + (k0 + 32) * 2, (char*)Bl[cur ^ 1] + tid * 16);
      GLOAD16(Bb + boff[1] + (k0 + 32) * 2, (char*)Bl[cur ^ 1] + 4096 + tid * 16);
    }
    f16x8 af[4], bf[4];
#pragma unroll
    for (int m = 0; m < 4; ++m) {
      const int row = wr + m * 16 + li;
      af[m] = *(const f16x8*)((const char*)Al[cur] + (row << 6) +
                              ((g ^ ((row >> 1) & 3)) << 4));
    }
#pragma unroll
    for (int n = 0; n < 4; ++n) {
      const int row = wc + n * 16 + li;
      bf[n] = *(const f16x8*)((const char*)Bl[cur] + (row << 6) +
                              ((g ^ ((row >> 1) & 3)) << 4));
    }
#pragma unroll
    for (int m = 0; m < 4; ++m)
#pragma unroll
      for (int n = 0; n < 4; ++n)
        acc[m][n] = __builtin_amdgcn_mfma_f32_16x16x32_f16(af[m], bf[n], acc[m][n], 0, 0, 0);
  }
#pragma unroll
  for (int m = 0; m < 4; ++m) {
    const int row = bm * 128 + wr + m * 16 + g * 4;
#pragma unroll
    for (int n = 0; n < 4; ++n) {
      const int col = bn * 128 + wc + n * 16 + li;
#pragma unroll
      for (int j = 0; j < 4; ++j)
        C[(size_t)(row + j) * N + col] = acc[m][n][j];
    }
  }
}

// ---------------------------------------------------------------- launch
extern "C" void kernel_launch(void* const* d_in, const int* in_sizes, int n_in,
                              void* d_out, int out_size, void* d_ws, size_t ws_size,
                              hipStream_t stream) {
  (void)in_sizes; (void)n_in; (void)out_size; (void)ws_size;
  const float* q = (const float*)d_in[0];
  const float* k = (const float*)d_in[1];
  const float* v = (const float*)d_in[2];
  const float* wq = (const float*)d_in[3];
  const float* wk = (const float*)d_in[4];
  const float* wv = (const float*)d_in[5];
  const float* wo = (const float*)d_in[6];
  const int* vl = (const int*)d_in[8];

  char* ws = (char*)d_ws;
  const size_t MB = 1u << 20;
  u16* AO = (u16*)(ws + 0 * MB);    // 8 MB (attn output, merged heads)
  u16* wqt = (u16*)(ws + 24 * MB);  // 2 MB each, transposed fp16
  u16* wkt = (u16*)(ws + 26 * MB);
  u16* wvt = (u16*)(ws + 28 * MB);
  u16* wot = (u16*)(ws + 30 * MB);
  u16* Qh = (u16*)(ws + 32 * MB);
  u16* Kh = (u16*)(ws + 40 * MB);
  u16* Vt = (u16*)(ws + 48 * MB);
  float* Vm = (float*)(ws + 56 * MB);  // 16 KB

  wtrans_kernel<<<dim3(16, 16, 4), 256, 0, stream>>>(wq, wk, wv, wo, wqt, wkt, wvt, wot);
  gemm_qkv_kernel<<<768, 256, 0, stream>>>(q, k, v, wqt, wkt, wvt, Qh, Kh, Vt, vl);
  vmean_kernel<<<64, 256, 0, stream>>>(Vt, Vm);
  attn_kernel<<<4096, 64, 0, stream>>>(Qh, Kh, Vt, Vm, vl, AO);
  gemm_out_kernel<<<256, 256, 0, stream>>>(AO, wot, (float*)d_out);
}